// Round 1
// 155.317 us; speedup vs baseline: 1.0078x; 1.0078x over previous
//
#include <hip/hip_runtime.h>

// GeodesicAttention: B=4, T=2048, D=1024, R=32
//   y = x @ U; logits[t,j] = 2 y_t.y_j - n_j  (row-const -n_t cancels)
//   KEY: max_j logit = n_t exactly (2ab - b^2 <= a^2, equality j=t), so
//   p[t,j] = exp(2 y_t.y_j - n_j - n_t) in (0,1] with NO online max/rescale.
// Round 7: FUSE scores+pv flash-style (P never hits HBM).
//   - ybf scaled by sqrt(2/ln2) so p = exp2(ybf_t.ybf_j - nj' - nt') is ONE
//     v_exp_f32 (no log2e mul). nj'+nt' folded into the score-MFMA C operand.
//   - per (t-tile 128, d-slab 128) block: loop j in 64-tiles; each wave
//     computes a 32t x 64j P strip (8 K=32 MFMAs), exp2+bf16-packs, and
//     ds_writes into the SAME XOR-swizzled As layout the PV reader used.
//   - Bs (xt) global_load_lds path unchanged; scores compute overlaps it.
//   - l = rowsum(P) computed locally per block (loop covers all j): no l
//     buffer, no atomics, no geo_scores kernel, no 32MB P write / 40MB fetch.
#define B_ 4
#define T_ 2048
#define D_ 1024
#define R_ 32
#define XSTR2 136  // prep LDS row stride in shorts (272B = 17*16B; row width 128)

typedef __attribute__((ext_vector_type(8))) short short8;
typedef __attribute__((ext_vector_type(4))) float f32x4;
typedef __attribute__((ext_vector_type(4))) unsigned short us4;
typedef __attribute__((ext_vector_type(8))) unsigned short us8;

__device__ __forceinline__ unsigned short f2bf(float f) {
  union { float f; unsigned u; } v; v.f = f;
  unsigned r = (v.u + 0x7fffu + ((v.u >> 16) & 1u)) >> 16;
  return (unsigned short)r;
}
__device__ __forceinline__ float bf2f(unsigned short h) {
  union { unsigned u; float f; } v; v.u = (unsigned)h << 16;
  return v.f;
}

// ---------------- Ut[r][d] = bf16(U[d][r]) ----------------
__global__ __launch_bounds__(256)
void geo_ut(const float* __restrict__ U, unsigned short* __restrict__ Ut) {
  __shared__ float tile[128][33];
  const int tid = threadIdx.x;
  const int d0 = blockIdx.x * 128;
  #pragma unroll
  for (int i = 0; i < 16; i++) {
    int e = i * 256 + tid;            // 0..4095, coalesced
    int d = e >> 5, r = e & 31;
    tile[d][r] = U[(size_t)(d0 + d) * R_ + r];
  }
  __syncthreads();
  const int r = tid >> 3, seg = tid & 7;   // 32 r-rows x 8 segs of 16 d
  us8 o0, o1;
  #pragma unroll
  for (int k = 0; k < 8; k++) o0[k] = f2bf(tile[seg * 16 + k][r]);
  #pragma unroll
  for (int k = 0; k < 8; k++) o1[k] = f2bf(tile[seg * 16 + 8 + k][r]);
  *(us8*)(Ut + (size_t)r * D_ + d0 + seg * 16) = o0;
  *(us8*)(Ut + (size_t)r * D_ + d0 + seg * 16 + 8) = o1;
}

// ---------------- prep: xt + partial y, one barrier, 4 blocks/CU ------------
__global__ __launch_bounds__(256)
void geo_prep(const float* __restrict__ x, const unsigned short* __restrict__ Ut,
              unsigned short* __restrict__ xt, float* __restrict__ y_part) {
  __shared__ unsigned short xs[2][32 * XSTR2];   // 2 x 8.7 KB
  const int b = blockIdx.y, slab = blockIdx.z;
  const int t0 = blockIdx.x * 32;
  const int d0 = slab * 256;
  const int tid = threadIdx.x, w = tid >> 6, lane = tid & 63;
  const int m = lane & 15, quad = lane >> 4;
  const int Mt = w & 1, Nt = w >> 1;
  const int lr = tid >> 3;              // load: t-row 0..31
  const int lc = (tid & 7) * 16;        // load: 16 d per thread per chunk

  const float* xb = x + ((size_t)b * T_ + t0 + lr) * D_ + d0 + lc;
  float4 v[2][4];
  #pragma unroll
  for (int ch = 0; ch < 2; ch++)
    #pragma unroll
    for (int i = 0; i < 4; i++)
      v[ch][i] = *(const float4*)(xb + ch * 128 + i * 4);
  #pragma unroll
  for (int ch = 0; ch < 2; ch++)
    #pragma unroll
    for (int i = 0; i < 4; i++) {
      us4 c;
      c[0] = f2bf(v[ch][i].x); c[1] = f2bf(v[ch][i].y);
      c[2] = f2bf(v[ch][i].z); c[3] = f2bf(v[ch][i].w);
      *(us4*)&xs[ch][lr * XSTR2 + lc + i * 4] = c;
    }
  __syncthreads();
  // transposed xt stores: per chunk, thread = (d-row 0..127, t-half), 2 us8
  {
    const int wd = tid >> 1, wt = (tid & 1) * 16;
    #pragma unroll
    for (int ch = 0; ch < 2; ch++) {
      us8 o0, o1;
      #pragma unroll
      for (int k = 0; k < 8; k++) {
        o0[k] = xs[ch][(wt + k) * XSTR2 + wd];
        o1[k] = xs[ch][(wt + 8 + k) * XSTR2 + wd];
      }
      unsigned short* xo = xt + ((size_t)b * D_ + d0 + ch * 128 + wd) * T_ + t0;
      *(us8*)(xo + wt) = o0;
      *(us8*)(xo + wt + 8) = o1;
    }
  }
  // partial y: A = x-tile rows (t), B = Ut rows (r), K = 256
  f32x4 acc = {0.f, 0.f, 0.f, 0.f};
  #pragma unroll
  for (int ch = 0; ch < 2; ch++)
    #pragma unroll
    for (int ks = 0; ks < 4; ks++) {
      short8 af = *(const short8*)&xs[ch][(Mt * 16 + m) * XSTR2 + ks * 32 + quad * 8];
      short8 bf = *(const short8*)(Ut + (size_t)(Nt * 16 + m) * D_ + d0 + ch * 128 + ks * 32 + quad * 8);
      acc = __builtin_amdgcn_mfma_f32_16x16x32_bf16(af, bf, acc, 0, 0, 0);
    }
  // C layout: row(t) = quad*4+reg, col(r) = m  -> 4 scalar stores
  float* yp = y_part + ((size_t)(slab * B_ + b) * T_ + t0 + Mt * 16 + quad * 4) * R_ + Nt * 16 + m;
  #pragma unroll
  for (int k = 0; k < 4; k++) yp[(size_t)k * R_] = acc[k];
}

// ---------------- reduce: y = sum_s y_part; ybf (exp2-scaled), nsq ----------
// SCALE = sqrt(2/ln2): then ybf_t.ybf_j - nj - nt = log2 exp(2y_t.y_j - ...)
__global__ __launch_bounds__(256)
void geo_reduce(const float* __restrict__ y_part, unsigned short* __restrict__ ybf,
                float* __restrict__ nsq) {
  const int tid = threadIdx.x;
  const size_t row = (size_t)blockIdx.x * 32 + (tid >> 3);   // flat b*T+t
  const int r0 = (tid & 7) * 4;
  f32x4 v = {0.f, 0.f, 0.f, 0.f};
  #pragma unroll
  for (int s = 0; s < 4; s++) {
    f32x4 p = *(const f32x4*)(y_part + ((size_t)s * B_ * T_ + row) * R_ + r0);
    #pragma unroll
    for (int k = 0; k < 4; k++) v[k] += p[k];
  }
  us4 pk;
  float part = 0.f;
  #pragma unroll
  for (int k = 0; k < 4; k++) {
    pk[k] = f2bf(1.69864446f * v[k]);   // sqrt(2/ln2)
    float b = bf2f(pk[k]);              // exactly what the score MFMA will dot
    part += b * b;
  }
  *(us4*)(ybf + row * R_ + r0) = pk;
  part += __shfl_xor(part, 1, 64);
  part += __shfl_xor(part, 2, 64);
  part += __shfl_xor(part, 4, 64);
  if ((tid & 7) == 0) nsq[row] = 0.5f * part;
}

// ---------------- fused: out[t, d-slab] = (exp2-P @ xt^T) / rowsum ----------
// Block = (t-tile 128) x (d-slab 128). Wave w: scores strip t in [w*32,w*32+32),
// PV quadrant wr=(w&1)*64, wc=(w>>1)*64. Loop j in 64-tiles (32 iters).
__global__ __launch_bounds__(256, 2)
void geo_fused(const unsigned short* __restrict__ ybf,
               const float* __restrict__ nsq,
               const unsigned short* __restrict__ xt,
               float* __restrict__ out) {
  __shared__ unsigned short As[128 * 64];   // P tile (bf16, XOR-swizzled)
  __shared__ unsigned short Bs[128 * 64];   // xt tile (bf16, XOR-swizzled)
  __shared__ float l_s[128];                // per-t row sums
  const int b = blockIdx.z;
  const int id = blockIdx.x;
  const int d0 = (id & 7) * 128;   // id%8 keyed to d-slab: each XCD reuses one xt panel
  const int t0 = (id >> 3) * 128;
  const int tid = threadIdx.x, w = tid >> 6, lane = tid & 63;
  const int m = lane & 15, quad = lane >> 4;
  const int wr = (w & 1) * 64, wc = (w >> 1) * 64;
  const int srow = lane >> 3, sslot = lane & 7;
  const int tw = w * 32;

  const unsigned short* yb = ybf + (size_t)b * T_ * R_;
  const float* nb = nsq + b * T_;
  const unsigned short* Xb = xt + ((size_t)b * D_ + d0) * T_;

  // hoisted t-side fragments
  short8 at[2]; float nnt[2]; float lsum[2] = {0.f, 0.f};
  #pragma unroll
  for (int tb = 0; tb < 2; tb++) {
    at[tb] = *(const short8*)(yb + (size_t)(t0 + tw + tb * 16 + m) * R_ + quad * 8);
    nnt[tb] = -nb[t0 + tw + tb * 16 + m];
  }

  f32x4 acc[4][4];
  #pragma unroll
  for (int i = 0; i < 4; i++)
    #pragma unroll
    for (int j = 0; j < 4; j++) acc[i][j] = (f32x4){0.f, 0.f, 0.f, 0.f};

  // prefetch j-tile 0 fragments
  short8 aj[4]; f32x4 njv[4];
  #pragma unroll
  for (int ja = 0; ja < 4; ja++) {
    aj[ja] = *(const short8*)(yb + (size_t)(ja * 16 + m) * R_ + quad * 8);
    njv[ja] = *(const f32x4*)(nb + ja * 16 + quad * 4);
  }

  for (int j0 = 0; j0 < T_; j0 += 64) {
    __syncthreads();   // prev PV done with As/Bs
    // stage V tile (d-rows x 64 j), pre-swizzled global source, linear LDS dest
    #pragma unroll
    for (int cc = 0; cc < 4; cc++) {
      const int row = w * 32 + cc * 8 + srow;
      const int gs = sslot ^ (row & 7);
      __builtin_amdgcn_global_load_lds(
          (const __attribute__((address_space(1))) void*)(Xb + (size_t)row * T_ + j0 + gs * 8),
          (__attribute__((address_space(3))) void*)(Bs + (w * 32 + cc * 8) * 64),
          16, 0, 0);
    }
    // rotate current fragments, prefetch next tile (overlaps scores+PV)
    short8 caj[4]; f32x4 cnj[4];
    #pragma unroll
    for (int ja = 0; ja < 4; ja++) { caj[ja] = aj[ja]; cnj[ja] = njv[ja]; }
    const int jn = (j0 + 64 < T_) ? j0 + 64 : 0;
    #pragma unroll
    for (int ja = 0; ja < 4; ja++) {
      aj[ja] = *(const short8*)(yb + (size_t)(jn + ja * 16 + m) * R_ + quad * 8);
      njv[ja] = *(const f32x4*)(nb + jn + ja * 16 + quad * 4);
    }
    // scores: c[r] = score(t = tw+tb*16+m, jloc = ja*16+quad*4+r); -nj-nt in C
    #pragma unroll
    for (int tb = 0; tb < 2; tb++) {
      const int trow = tw + tb * 16 + m;   // local t row 0..127; trow&7 == m&7
      #pragma unroll
      for (int ja = 0; ja < 4; ja++) {
        f32x4 cin;
        #pragma unroll
        for (int r = 0; r < 4; r++) cin[r] = nnt[tb] - cnj[ja][r];
        f32x4 c = __builtin_amdgcn_mfma_f32_16x16x32_bf16(caj[ja], at[tb], cin, 0, 0, 0);
        us4 pk; float ls = 0.f;
        #pragma unroll
        for (int r = 0; r < 4; r++) {
          float p = __builtin_amdgcn_exp2f(c[r]);
          ls += p;
          pk[r] = f2bf(p);
        }
        lsum[tb] += ls;
        // store src 16B-block sb at physical block sb^(trow&7), +8B if quad odd
        const int sb = ja * 2 + (quad >> 1);
        char* dst = (char*)As + trow * 128 + ((sb ^ (trow & 7)) * 16) + (quad & 1) * 8;
        *(us4*)dst = pk;
      }
    }
    __syncthreads();   // As written + Bs arrived (compiler drains vmcnt)
    // PV: identical to the verified m97-style reader
    #pragma unroll
    for (int ks = 0; ks < 2; ks++) {
      short8 af[4], bf[4];
      #pragma unroll
      for (int i = 0; i < 4; i++) {
        const int ra = wr + i * 16 + m;
        af[i] = *(const short8*)(As + ra * 64 + (((ks * 4 + quad) ^ (m & 7)) * 8));
        const int cd = wc + i * 16 + m;
        bf[i] = *(const short8*)(Bs + cd * 64 + (((ks * 4 + quad) ^ (m & 7)) * 8));
      }
      #pragma unroll
      for (int rb = 0; rb < 4; rb++)
        #pragma unroll
        for (int cb = 0; cb < 4; cb++)
          acc[rb][cb] = __builtin_amdgcn_mfma_f32_16x16x32_bf16(af[rb], bf[cb], acc[rb][cb], 0, 0, 0);
    }
  }
  // full row sums: butterfly over quads, lanes 0..15 publish both strips
  #pragma unroll
  for (int tb = 0; tb < 2; tb++) {
    lsum[tb] += __shfl_xor(lsum[tb], 16, 64);
    lsum[tb] += __shfl_xor(lsum[tb], 32, 64);
  }
  if (quad == 0) { l_s[tw + m] = lsum[0]; l_s[tw + 16 + m] = lsum[1]; }
  __syncthreads();
  // epilogue: out = acc / l   (C layout: row = quad*4+r, col = m)
  float* ob = out + ((size_t)b * T_ + t0 + wr) * D_ + d0 + wc;
  #pragma unroll
  for (int rb = 0; rb < 4; rb++) {
    f32x4 lv = *(const f32x4*)&l_s[wr + rb * 16 + quad * 4];
    f32x4 inv;
    #pragma unroll
    for (int r = 0; r < 4; r++) inv[r] = 1.f / lv[r];
    #pragma unroll
    for (int cb = 0; cb < 4; cb++)
      #pragma unroll
      for (int r = 0; r < 4; r++)
        ob[(size_t)(rb * 16 + quad * 4 + r) * D_ + cb * 16 + m] = acc[rb][cb][r] * inv[r];
  }
}

extern "C" void kernel_launch(void* const* d_in, const int* in_sizes, int n_in,
                              void* d_out, int out_size, void* d_ws, size_t ws_size,
                              hipStream_t stream) {
  const float* x = (const float*)d_in[0];
  const float* U = (const float*)d_in[1];
  float* out = (float*)d_out;

  const size_t xt_b  = (size_t)B_ * D_ * T_ * 2;      // 16 MB
  const size_t ybf_b = (size_t)B_ * T_ * R_ * 2;      // 512 KB
  const size_t nsq_b = (size_t)B_ * T_ * 4;           // 32 KB
  const size_t ut_b  = (size_t)D_ * R_ * 2;           // 64 KB
  const size_t yp_b  = (size_t)4 * B_ * T_ * R_ * 4;  // 4 MB partial y

  char* wp = (char*)d_ws;
  unsigned short* xtp = (unsigned short*)wp;                 wp += xt_b;
  unsigned short* ybf = (unsigned short*)wp;                 wp += ybf_b;
  float* nsq = (float*)wp;                                   wp += nsq_b;
  unsigned short* Utp = (unsigned short*)wp;                 wp += ut_b;
  float* ypart = (float*)wp;                                 wp += yp_b;
  (void)ws_size; (void)in_sizes; (void)n_in; (void)out_size;

  hipLaunchKernelGGL(geo_ut, dim3(D_ / 128), dim3(256), 0, stream, U, Utp);
  hipLaunchKernelGGL(geo_prep, dim3(T_ / 32, B_, 4), dim3(256), 0, stream,
                     x, Utp, xtp, ypart);
  hipLaunchKernelGGL(geo_reduce, dim3(B_ * T_ / 32), dim3(256), 0, stream,
                     ypart, ybf, nsq);
  hipLaunchKernelGGL(geo_fused, dim3((T_ / 128) * (D_ / 128), 1, B_), dim3(256), 0, stream,
                     ybf, nsq, xtp, out);
}